// Round 7
// baseline (36.093 us; speedup 1.0000x reference)
//
#include <hip/hip_runtime.h>

typedef __attribute__((ext_vector_type(4))) float f32x4;

#define N_MOLS   2000
#define NATOM    64
#define PPM      (NATOM * (NATOM - 1))   // 4032 pairs per molecule
#define NPAIRS   (N_MOLS * PPM)          // 8,064,000
#define NGROUPS  (NPAIRS / 4)            // 2,016,000 = 7875 blocks * 256 threads exactly

__global__ __launch_bounds__(256, 8) void nl_pairs_kernel(const float* __restrict__ pos,
                                                          float* __restrict__ out) {
    // 12 KB LDS, but partitioned per-wave (3 KB each) -> NO block barrier needed.
    __shared__ float sR[4 * 768];

    const int tid  = threadIdx.x;
    const int lane = tid & 63;
    const int wv   = tid >> 6;
    const int gblk = blockIdx.x * 256;      // first group of this block

    const int k0  = (gblk + tid) * 4;       // this thread's first pair
    const int mol = k0 / PPM;
    int       kl  = k0 - mol * PPM;
    const int base = mol * NATOM;
    int i = kl / 63;                        // local i row
    int t = kl - i * 63;                    // slot within row (j skips i)

    // positions straight from global (768 B/molecule, L1/L2-resident; R3/R6
    // proved the gather path is not the limiter)
    const float* mp = pos + (long)base * 3;
    float pix = mp[i*3+0], piy = mp[i*3+1], piz = mp[i*3+2];

    f32x4 vi, vj, vd;
    float rr[12];

    #pragma unroll
    for (int u = 0; u < 4; ++u) {
        const int j = (t < i) ? t : (t + 1);
        const float pjx = mp[j*3+0], pjy = mp[j*3+1], pjz = mp[j*3+2];

        // strict IEEE f32, no FMA contraction -> bit-exact vs numpy:
        // d = sqrt((dx*dx + dy*dy) + dz*dz)
        const float dx = __fsub_rn(pjx, pix);
        const float dy = __fsub_rn(pjy, piy);
        const float dz = __fsub_rn(pjz, piz);
        const float d2 = __fadd_rn(__fadd_rn(__fmul_rn(dx, dx), __fmul_rn(dy, dy)),
                                   __fmul_rn(dz, dz));
        const float d  = __fsqrt_rn(d2);
        const bool  in = (d <= 5.0f);

        vi[u] = (float)(base + i);          // exact: < 2^24
        vj[u] = (float)(base + j);
        vd[u] = in ? d : 0.0f;
        rr[3*u+0] = in ? dx : 0.0f;
        rr[3*u+1] = in ? dy : 0.0f;
        rr[3*u+2] = in ? dz : 0.0f;

        if (u < 3) {                        // advance (i,t) within the molecule
            ++t;
            if (t == 63) { t = 0; ++i; pix = mp[i*3+0]; piy = mp[i*3+1]; piz = mp[i*3+2]; }
        }
    }

    // i/j/d streams: dense 16B/lane cached stores
    *reinterpret_cast<f32x4*>(out + k0)            = vi;
    *reinterpret_cast<f32x4*>(out + NPAIRS + k0)   = vj;
    *reinterpret_cast<f32x4*>(out + 2*NPAIRS + k0) = vd;

    // Wave-local r transpose: each wave owns sR[wv*768 .. +768). Writes at
    // 48-B lane stride (b128: conflict-free, each 8-lane phase hits all 32
    // banks), reads dense. In-wave RAW ordered by lgkmcnt(0); no __syncthreads.
    float* sw = sR + wv * 768;
    *reinterpret_cast<f32x4*>(sw + 12*lane + 0) = f32x4{rr[0], rr[1], rr[2],  rr[3]};
    *reinterpret_cast<f32x4*>(sw + 12*lane + 4) = f32x4{rr[4], rr[5], rr[6],  rr[7]};
    *reinterpret_cast<f32x4*>(sw + 12*lane + 8) = f32x4{rr[8], rr[9], rr[10], rr[11]};

    __asm__ volatile("s_waitcnt lgkmcnt(0)" ::: "memory");
    __builtin_amdgcn_sched_barrier(0);      // rule #18: pin reads after the wait

    // this wave's r region: 768 consecutive floats at pair base (gblk+64*wv)*4
    float* rv = out + (long)3 * NPAIRS + (long)12 * (gblk + 64 * wv);
    *reinterpret_cast<f32x4*>(rv + 4*lane + 0)    = *reinterpret_cast<f32x4*>(sw + 4*lane + 0);
    *reinterpret_cast<f32x4*>(rv + 4*lane + 256)  = *reinterpret_cast<f32x4*>(sw + 4*lane + 256);
    *reinterpret_cast<f32x4*>(rv + 4*lane + 512)  = *reinterpret_cast<f32x4*>(sw + 4*lane + 512);
}

extern "C" void kernel_launch(void* const* d_in, const int* in_sizes, int n_in,
                              void* d_out, int out_size, void* d_ws, size_t ws_size,
                              hipStream_t stream) {
    const float* pos = (const float*)d_in[0];
    float* out = (float*)d_out;
    const int blocks = NGROUPS / 256;       // 7875, exact
    nl_pairs_kernel<<<blocks, 256, 0, stream>>>(pos, out);
}

// Round 8
// 35.336 us; speedup vs baseline: 1.0214x; 1.0214x over previous
//
#include <hip/hip_runtime.h>

typedef __attribute__((ext_vector_type(4))) float f32x4;

#define N_MOLS   2000
#define NATOM    64
#define PPM      (NATOM * (NATOM - 1))   // 4032 pairs per molecule
#define NPAIRS   (N_MOLS * PPM)          // 8,064,000
#define NGROUPS  (NPAIRS / 4)            // 2,016,000 = 7875 blocks * 256 threads exactly

__global__ __launch_bounds__(256) void nl_pairs_kernel(const float* __restrict__ pos,
                                                       float* __restrict__ out) {
    // A block covers 1024 consecutive pairs -> at most 2 molecules (1536 B of positions).
    __shared__ float sPos[2 * NATOM * 3];   // 384 floats
    __shared__ f32x4 sR[768];               // 12 KB: block's r_ij, staged for dense stores

    const int tid    = threadIdx.x;
    const int gblk   = blockIdx.x * 256;    // first group of this block
    const int k0_blk = gblk * 4;            // first pair of this block
    const int mol0   = k0_blk / PPM;        // first molecule touched

    // stage molecules [mol0, mol0+1] (clamped) with coalesced float4 loads
    const int nvec = (mol0 >= N_MOLS - 1) ? 48 : 96;
    if (tid < nvec) {
        reinterpret_cast<f32x4*>(sPos)[tid] =
            reinterpret_cast<const f32x4*>(pos + (long)mol0 * (NATOM * 3))[tid];
    }
    __syncthreads();

    const int k0  = (gblk + tid) * 4;       // this thread's first pair
    const int mol = k0 / PPM;
    int       kl  = k0 - mol * PPM;
    const int base = mol * NATOM;
    int i = kl / 63;                        // local i row
    int t = kl - i * 63;                    // slot within row (j skips i)

    const float* mp = sPos + (mol - mol0) * (NATOM * 3);
    float pix = mp[i*3+0], piy = mp[i*3+1], piz = mp[i*3+2];

    f32x4 vi, vj, vd;
    float rr[12];

    #pragma unroll
    for (int u = 0; u < 4; ++u) {
        const int j = (t < i) ? t : (t + 1);
        const float pjx = mp[j*3+0], pjy = mp[j*3+1], pjz = mp[j*3+2];

        // strict IEEE f32, no FMA contraction -> bit-exact vs numpy:
        // d = sqrt((dx*dx + dy*dy) + dz*dz)
        const float dx = __fsub_rn(pjx, pix);
        const float dy = __fsub_rn(pjy, piy);
        const float dz = __fsub_rn(pjz, piz);
        const float d2 = __fadd_rn(__fadd_rn(__fmul_rn(dx, dx), __fmul_rn(dy, dy)),
                                   __fmul_rn(dz, dz));
        const float d  = __fsqrt_rn(d2);
        const bool  in = (d <= 5.0f);

        vi[u] = (float)(base + i);          // exact: < 2^24
        vj[u] = (float)(base + j);
        vd[u] = in ? d : 0.0f;
        rr[3*u+0] = in ? dx : 0.0f;
        rr[3*u+1] = in ? dy : 0.0f;
        rr[3*u+2] = in ? dz : 0.0f;

        if (u < 3) {                        // advance (i,t) within the molecule
            ++t;
            if (t == 63) { t = 0; ++i; pix = mp[i*3+0]; piy = mp[i*3+1]; piz = mp[i*3+2]; }
        }
    }

    // i/j/d streams: dense 16B/lane cached stores straight from registers
    *reinterpret_cast<f32x4*>(out + k0)            = vi;
    *reinterpret_cast<f32x4*>(out + NPAIRS + k0)   = vj;
    *reinterpret_cast<f32x4*>(out + 2*NPAIRS + k0) = vd;

    // r stream: transpose through LDS so the global stores are fully dense.
    // LDS write (48-B lane stride) and read (16-B stride) are both
    // bank-conflict-free for b128 (each 8-lane phase covers all 32 banks).
    sR[3*tid + 0] = f32x4{rr[0], rr[1], rr[2],  rr[3]};
    sR[3*tid + 1] = f32x4{rr[4], rr[5], rr[6],  rr[7]};
    sR[3*tid + 2] = f32x4{rr[8], rr[9], rr[10], rr[11]};
    __syncthreads();

    // block's r region = 3072 floats = 768 f32x4, written dense (16B lane stride)
    f32x4* rv = reinterpret_cast<f32x4*>(out + (long)3 * NPAIRS + (long)3 * k0_blk);
    rv[tid]       = sR[tid];
    rv[tid + 256] = sR[tid + 256];
    rv[tid + 512] = sR[tid + 512];
}

extern "C" void kernel_launch(void* const* d_in, const int* in_sizes, int n_in,
                              void* d_out, int out_size, void* d_ws, size_t ws_size,
                              hipStream_t stream) {
    const float* pos = (const float*)d_in[0];
    float* out = (float*)d_out;
    const int blocks = NGROUPS / 256;       // 7875, exact
    nl_pairs_kernel<<<blocks, 256, 0, stream>>>(pos, out);
}